// Round 15
// baseline (569.251 us; speedup 1.0000x reference)
//
#include <hip/hip_runtime.h>
#include <cstddef>

#define T_SEQ 11
#define STEPS 80
#define SRC (-1.44269504f)
#define SNC ( 2.88539008f)

typedef _Float16 f16;
typedef _Float16 f16x4 __attribute__((ext_vector_type(4)));
typedef _Float16 f16x8 __attribute__((ext_vector_type(8)));
typedef float    f32x4 __attribute__((ext_vector_type(4)));

// ---- LDS layout (halves) ----------------------------------------------
#define W0H   0        // l0 Whh (192 x 64, swizzled)      12288 halves
#define WPADO 12288    // l0 x-side, 192 x 32 padded        6144 halves
#define HB    18432    // 4 waves x (h0: 2x1024, h1: 2x1024) = 16384 halves
#define BIASH 34816    // f32 region: 8 arrays x 64 = 512 floats
#define LDS_BYTES (34816*2 + 512*4)   // 71680 B

__device__ __forceinline__ f32x4 mfma16(f16x8 a, f16x8 b, f32x4 c) {
    return __builtin_amdgcn_mfma_f32_16x16x32_f16(a, b, c, 0, 0, 0);
}

// ---- staging (256-thread block) ---------------------------------------
__device__ __forceinline__ void stage_w(f16* lds, int dst, const float* __restrict__ W, int tid) {
    for (int c = tid; c < 1536; c += 256) {
        const int row = c >> 3, kc = c & 7;
        const float sc = (row < 128) ? SRC : SNC;
        const float* p = W + row * 64 + kc * 8;
        f16x8 v;
        #pragma unroll
        for (int i = 0; i < 8; ++i) v[i] = (f16)(sc * p[i]);
        *(f16x8*)(lds + dst + row * 64 + ((kc ^ (row & 7)) << 3)) = v;
    }
}
__device__ __forceinline__ void stage_pad(f16* lds, const float* __restrict__ Wih0, int tid) {
    for (int c = tid; c < 768; c += 256) {
        const int row = c >> 2, kc = c & 3;
        const float sc = (row < 128) ? SRC : SNC;
        f16x8 v;
        #pragma unroll
        for (int i = 0; i < 8; ++i) v[i] = (f16)0.f;
        if (kc == 0) { v[0] = (f16)(sc * Wih0[row * 2]); v[1] = (f16)(sc * Wih0[row * 2 + 1]); }
        *(f16x8*)(lds + WPADO + row * 32 + ((kc ^ (row & 3)) << 3)) = v;
    }
}
__device__ __forceinline__ void stage_bias(float* bb, int base, const float* __restrict__ bih,
                                           const float* __restrict__ bhh, int tid) {
    for (int t = tid; t < 256; t += 256) {
        const int a = t >> 6, j = t & 63;
        float v;
        if (a == 0)      v = SRC * (bih[j] + bhh[j]);
        else if (a == 1) v = SRC * (bih[64 + j] + bhh[64 + j]);
        else if (a == 2) v = SNC * bih[128 + j];
        else             v = SNC * bhh[128 + j];
        bb[(base + a) * 64 + j] = v;
    }
}

// A-frag from global: lane holds sc*W[row][k0..k0+7].
__device__ __forceinline__ f16x8 wfrag(const float* __restrict__ W, int row, int k0, float sc) {
    f16x8 r;
    #pragma unroll
    for (int i = 0; i < 8; ++i) r[i] = (f16)(sc * W[row * 64 + k0 + i]);
    return r;
}
// Register-cached A-frags: [ks*4+mt], all 64 j (wave owns all gates).
__device__ __forceinline__ void load_wregs(f16x8 (&R)[8], f16x8 (&Z)[8], f16x8 (&N)[8],
                                           const float* __restrict__ W, int col, int quad) {
    #pragma unroll
    for (int ks = 0; ks < 2; ++ks) {
        #pragma unroll
        for (int mt = 0; mt < 4; ++mt) {
            const int k0 = ks * 32 + quad * 8;
            R[ks * 4 + mt] = wfrag(W, mt * 16 + col,       k0, SRC);
            Z[ks * 4 + mt] = wfrag(W, 64  + mt * 16 + col, k0, SRC);
            N[ks * 4 + mt] = wfrag(W, 128 + mt * 16 + col, k0, SNC);
        }
    }
}

struct Lane {
    int col, quad, c7, colr, x0, x1, xp;
    int wo[4];
};

__device__ __forceinline__ void gates4(f32x4 aR, f32x4 aZ, f32x4 aNi, f32x4 aNh,
                                       f16x4& ho, f16* dst)
{
    f16x4 o;
    #pragma unroll
    for (int i = 0; i < 4; ++i) {
        const float r = __builtin_amdgcn_rcpf(1.f + __builtin_amdgcn_exp2f(aR[i]));
        const float z = __builtin_amdgcn_rcpf(1.f + __builtin_amdgcn_exp2f(aZ[i]));
        const float n = 1.f - 2.f * __builtin_amdgcn_rcpf(1.f + __builtin_amdgcn_exp2f(aNi[i] + r * aNh[i]));
        const float h = n + z * ((float)ho[i] - n);
        o[i] = (f16)h;
    }
    ho = o;
    *(f16x4*)dst = o;
}

// l0 cell: h-side A from LDS W0H, x-side = K=32 MFMA from WPADO; 2 n-tiles.
// A-frags loaded once per mt, reused for both nt (halves weight traffic).
__device__ __forceinline__ void cell_l0(f16* lds, const Lane& L, f16x4 (&ho)[4][2],
                                        const f16x8 (&xpb)[2], int h0b)
{
    const float* bb = (const float*)(lds + BIASH);
    f16x8 hb[2][2];
    #pragma unroll
    for (int nt = 0; nt < 2; ++nt) {
        hb[nt][0] = *(const f16x8*)(lds + h0b + nt * 1024 + L.colr + L.x0);
        hb[nt][1] = *(const f16x8*)(lds + h0b + nt * 1024 + L.colr + L.x1);
    }
    #pragma unroll
    for (int mt = 0; mt < 4; ++mt) {
        const int bj = mt * 16 + L.quad * 4;
        f32x4 bR  = *(const f32x4*)(bb + 0 * 64 + bj);
        f32x4 bZ  = *(const f32x4*)(bb + 1 * 64 + bj);
        f32x4 bNi = *(const f32x4*)(bb + 2 * 64 + bj);
        f32x4 bNh = *(const f32x4*)(bb + 3 * 64 + bj);
        const int ar = (mt * 16 + L.col) * 64;
        f16x8 hR0 = *(const f16x8*)(lds + W0H        + ar + L.x0);
        f16x8 hR1 = *(const f16x8*)(lds + W0H        + ar + L.x1);
        f16x8 hZ0 = *(const f16x8*)(lds + W0H + 4096 + ar + L.x0);
        f16x8 hZ1 = *(const f16x8*)(lds + W0H + 4096 + ar + L.x1);
        f16x8 hN0 = *(const f16x8*)(lds + W0H + 8192 + ar + L.x0);
        f16x8 hN1 = *(const f16x8*)(lds + W0H + 8192 + ar + L.x1);
        const int pr = (mt * 16 + L.col) * 32;
        f16x8 pR = *(const f16x8*)(lds + WPADO        + pr + L.xp);
        f16x8 pZ = *(const f16x8*)(lds + WPADO + 2048 + pr + L.xp);
        f16x8 pN = *(const f16x8*)(lds + WPADO + 4096 + pr + L.xp);
        #pragma unroll
        for (int nt = 0; nt < 2; ++nt) {
            f32x4 aR  = mfma16(hR0, hb[nt][0], bR);  aR  = mfma16(hR1, hb[nt][1], aR);
            f32x4 aZ  = mfma16(hZ0, hb[nt][0], bZ);  aZ  = mfma16(hZ1, hb[nt][1], aZ);
            f32x4 aNh = mfma16(hN0, hb[nt][0], bNh); aNh = mfma16(hN1, hb[nt][1], aNh);
            aR = mfma16(pR, xpb[nt], aR);
            aZ = mfma16(pZ, xpb[nt], aZ);
            f32x4 aNi = mfma16(pN, xpb[nt], bNi);
            gates4(aR, aZ, aNi, aNh, ho[mt][nt], lds + h0b + nt * 1024 + L.wo[mt]);
        }
    }
}

// l1 cell: both A-operand sets (Wih1, Whh1) register-resident; 2 n-tiles.
__device__ __forceinline__ void cell_l1(f16* lds, const Lane& L, f16x4 (&ho)[4][2],
    const f16x8 (&cR)[8], const f16x8 (&cZ)[8], const f16x8 (&cN)[8],
    const f16x8 (&xR)[8], const f16x8 (&xZ)[8], const f16x8 (&xN)[8],
    int h0b, int h1b)
{
    const float* bb = (const float*)(lds + BIASH);
    f16x8 xb[2][2], hv[2][2];
    #pragma unroll
    for (int nt = 0; nt < 2; ++nt) {
        xb[nt][0] = *(const f16x8*)(lds + h0b + nt * 1024 + L.colr + L.x0);
        xb[nt][1] = *(const f16x8*)(lds + h0b + nt * 1024 + L.colr + L.x1);
        hv[nt][0] = *(const f16x8*)(lds + h1b + nt * 1024 + L.colr + L.x0);
        hv[nt][1] = *(const f16x8*)(lds + h1b + nt * 1024 + L.colr + L.x1);
    }
    #pragma unroll
    for (int mt = 0; mt < 4; ++mt) {
        const int bj = mt * 16 + L.quad * 4;
        f32x4 bR  = *(const f32x4*)(bb + 4 * 64 + bj);
        f32x4 bZ  = *(const f32x4*)(bb + 5 * 64 + bj);
        f32x4 bNi = *(const f32x4*)(bb + 6 * 64 + bj);
        f32x4 bNh = *(const f32x4*)(bb + 7 * 64 + bj);
        #pragma unroll
        for (int nt = 0; nt < 2; ++nt) {
            f32x4 aR  = mfma16(cR[mt], hv[nt][0], bR);
            f32x4 aZ  = mfma16(cZ[mt], hv[nt][0], bZ);
            f32x4 aNh = mfma16(cN[mt], hv[nt][0], bNh);
            aR  = mfma16(cR[4 + mt], hv[nt][1], aR);
            aZ  = mfma16(cZ[4 + mt], hv[nt][1], aZ);
            aNh = mfma16(cN[4 + mt], hv[nt][1], aNh);
            aR  = mfma16(xR[mt], xb[nt][0], aR);
            aZ  = mfma16(xZ[mt], xb[nt][0], aZ);
            f32x4 aNi = mfma16(xN[mt], xb[nt][0], bNi);
            aR  = mfma16(xR[4 + mt], xb[nt][1], aR);
            aZ  = mfma16(xZ[4 + mt], xb[nt][1], aZ);
            aNi = mfma16(xN[4 + mt], xb[nt][1], aNi);
            gates4(aR, aZ, aNi, aNh, ho[mt][nt], lds + h1b + nt * 1024 + L.wo[mt]);
        }
    }
}

__global__ __launch_bounds__(256, 1)
void gru_wave4(
    const float* __restrict__ x,
    const float* __restrict__ eWih0, const float* __restrict__ eWhh0,
    const float* __restrict__ ebih0, const float* __restrict__ ebhh0,
    const float* __restrict__ eWih1, const float* __restrict__ eWhh1,
    const float* __restrict__ ebih1, const float* __restrict__ ebhh1,
    const float* __restrict__ dWih0, const float* __restrict__ dWhh0,
    const float* __restrict__ dbih0, const float* __restrict__ dbhh0,
    const float* __restrict__ dWih1, const float* __restrict__ dWhh1,
    const float* __restrict__ dbih1, const float* __restrict__ dbhh1,
    const float* __restrict__ fcW,  const float* __restrict__ fcb,
    float* __restrict__ out)
{
    extern __shared__ f16 lds[];
    float* bb = (float*)(lds + BIASH);
    const int tid  = threadIdx.x;
    const int lane = tid & 63;
    const int wv   = __builtin_amdgcn_readfirstlane(tid >> 6);   // 0..3

    Lane L;
    L.col  = lane & 15;
    L.quad = lane >> 4;
    L.c7   = L.col & 7;
    L.colr = L.col * 64;
    L.x0   = (L.quad ^ L.c7) << 3;
    L.x1   = ((4 + L.quad) ^ L.c7) << 3;
    L.xp   = (L.quad ^ (L.col & 3)) << 3;
    #pragma unroll
    for (int mt = 0; mt < 4; ++mt)
        L.wo[mt] = L.colr + (((2 * mt + (L.quad >> 1)) ^ L.c7) << 3) + ((L.quad & 1) << 2);

    const int rowb = blockIdx.x * 128 + wv * 32;   // 32 rows per wave
    const int h0b  = HB + wv * 4096;
    const int h1b  = h0b + 2048;

    // ---- encoder-phase staging ----
    stage_w(lds, W0H, eWhh0, tid);
    stage_pad(lds, eWih0, tid);
    stage_bias(bb, 0, ebih0, ebhh0, tid);
    stage_bias(bb, 4, ebih1, ebhh1, tid);
    {
        f16x8 z;
        #pragma unroll
        for (int i = 0; i < 8; ++i) z[i] = (f16)0.f;
        for (int k = lane; k < 512; k += 64) *(f16x8*)(lds + h0b + k * 8) = z;
    }
    f16x8 c1R[8], c1Z[8], c1N[8];   // Whh1
    f16x8 x1R[8], x1Z[8], x1N[8];   // Wih1
    load_wregs(c1R, c1Z, c1N, eWhh1, L.col, L.quad);
    load_wregs(x1R, x1Z, x1N, eWih1, L.col, L.quad);
    f16x4 ho0[4][2], ho1[4][2];
    #pragma unroll
    for (int m = 0; m < 4; ++m) {
        #pragma unroll
        for (int nt = 0; nt < 2; ++nt) {
            #pragma unroll
            for (int i = 0; i < 4; ++i) { ho0[m][nt][i] = (f16)0.f; ho1[m][nt][i] = (f16)0.f; }
        }
    }
    __syncthreads();

    const float* xr0 = x + (size_t)(rowb + L.col) * (T_SEQ * 2);
    const float* xr1 = x + (size_t)(rowb + 16 + L.col) * (T_SEQ * 2);
    f16x8 zf;
    #pragma unroll
    for (int i = 0; i < 8; ++i) zf[i] = (f16)0.f;

    // ---- encoder: barrier-free ----
    #pragma unroll 1
    for (int t = 0; t < T_SEQ; ++t) {
        f16x8 xpb[2] = {zf, zf};
        if (L.quad == 0) {
            const float2 a = *(const float2*)(xr0 + t * 2);
            const float2 b = *(const float2*)(xr1 + t * 2);
            xpb[0][0] = (f16)a.x; xpb[0][1] = (f16)a.y;
            xpb[1][0] = (f16)b.x; xpb[1][1] = (f16)b.y;
        }
        cell_l0(lds, L, ho0, xpb, h0b);
        cell_l1(lds, L, ho1, c1R, c1Z, c1N, x1R, x1Z, x1N, h0b, h1b);
    }

    // ---- phase switch ----
    __syncthreads();
    stage_w(lds, W0H, dWhh0, tid);
    stage_pad(lds, dWih0, tid);
    stage_bias(bb, 0, dbih0, dbhh0, tid);
    stage_bias(bb, 4, dbih1, dbhh1, tid);
    load_wregs(c1R, c1Z, c1N, dWhh1, L.col, L.quad);
    load_wregs(x1R, x1Z, x1N, dWih1, L.col, L.quad);
    __syncthreads();

    f16x8 fcf0 = zf, fcf1 = zf;
    if (L.col < 2) {
        #pragma unroll
        for (int i = 0; i < 8; ++i) {
            fcf0[i] = (f16)fcW[L.col * 64 + L.quad * 8 + i];
            fcf1[i] = (f16)fcW[L.col * 64 + 32 + L.quad * 8 + i];
        }
    }
    f32x4 pb;
    #pragma unroll
    for (int rg = 0; rg < 4; ++rg) pb[rg] = (L.quad == 0 && rg < 2) ? fcb[rg] : 0.f;

    float* __restrict__ op0 = out + (size_t)(rowb + L.col) * (STEPS * 2);
    float* __restrict__ op1 = out + (size_t)(rowb + 16 + L.col) * (STEPS * 2);

    // decoder step-0 x-input = last encoder x (same lane slots as pred).
    f16x8 xpb[2] = {zf, zf};
    if (L.quad == 0) {
        const float2 a = *(const float2*)(xr0 + (T_SEQ - 1) * 2);
        const float2 b = *(const float2*)(xr1 + (T_SEQ - 1) * 2);
        xpb[0][0] = (f16)a.x; xpb[0][1] = (f16)a.y;
        xpb[1][0] = (f16)b.x; xpb[1][1] = (f16)b.y;
    }

    // ---- decoder: uniform, barrier-free; pred feeds back in-lane ----
    #pragma unroll 1
    for (int s = 0; s < STEPS; ++s) {
        cell_l0(lds, L, ho0, xpb, h0b);
        cell_l1(lds, L, ho1, c1R, c1Z, c1N, x1R, x1Z, x1N, h0b, h1b);
        #pragma unroll
        for (int nt = 0; nt < 2; ++nt) {
            f16x8 b0 = *(const f16x8*)(lds + h1b + nt * 1024 + L.colr + L.x0);
            f16x8 b1 = *(const f16x8*)(lds + h1b + nt * 1024 + L.colr + L.x1);
            f32x4 p = mfma16(fcf0, b0, pb);
            p = mfma16(fcf1, b1, p);
            xpb[nt] = zf;
            if (L.quad == 0) {
                float* op = nt ? op1 : op0;
                *(float2*)(op + s * 2) = make_float2(p[0], p[1]);
                xpb[nt][0] = (f16)p[0];
                xpb[nt][1] = (f16)p[1];
            }
        }
    }
}

extern "C" void kernel_launch(void* const* d_in, const int* in_sizes, int n_in,
                              void* d_out, int out_size, void* d_ws, size_t ws_size,
                              hipStream_t stream) {
    (void)n_in; (void)out_size; (void)d_ws; (void)ws_size;

    const float* x     = (const float*)d_in[0];
    const float* eWih0 = (const float*)d_in[1];
    const float* eWhh0 = (const float*)d_in[2];
    const float* ebih0 = (const float*)d_in[3];
    const float* ebhh0 = (const float*)d_in[4];
    const float* eWih1 = (const float*)d_in[5];
    const float* eWhh1 = (const float*)d_in[6];
    const float* ebih1 = (const float*)d_in[7];
    const float* ebhh1 = (const float*)d_in[8];
    const float* dWih0 = (const float*)d_in[9];
    const float* dWhh0 = (const float*)d_in[10];
    const float* dbih0 = (const float*)d_in[11];
    const float* dbhh0 = (const float*)d_in[12];
    const float* dWih1 = (const float*)d_in[13];
    const float* dWhh1 = (const float*)d_in[14];
    const float* dbih1 = (const float*)d_in[15];
    const float* dbhh1 = (const float*)d_in[16];
    const float* fcW   = (const float*)d_in[17];
    const float* fcb   = (const float*)d_in[18];
    float* out = (float*)d_out;

    hipFuncSetAttribute((const void*)gru_wave4,
        hipFuncAttributeMaxDynamicSharedMemorySize, LDS_BYTES);

    const int b = in_sizes[0] / (T_SEQ * 2);   // 32768
    dim3 grid(b / 128), block(256);
    hipLaunchKernelGGL(gru_wave4, grid, block, LDS_BYTES, stream,
        x, eWih0, eWhh0, ebih0, ebhh0, eWih1, eWhh1, ebih1, ebhh1,
        dWih0, dWhh0, dbih0, dbhh0, dWih1, dWhh1, dbih1, dbhh1,
        fcW, fcb, out);
}